// Round 1
// baseline (1064.850 us; speedup 1.0000x reference)
//
#include <hip/hip_runtime.h>
#include <math.h>

#define SPLINE_DIM 47   // 3*16-1
#define CIN 48
#define NH1 128
#define NH2 128
#define NCOLS 1504      // 32 * 47
#define ROWS 64

__device__ __forceinline__ float softplus_f(float v) {
    float r = log1pf(expf(-fabsf(v)));
    return v > 0.f ? v + r : r;
}
__device__ __forceinline__ float swish_f(float a) {
    return a / (1.f + expf(-a));
}

__launch_bounds__(256)
__global__ void nsc_fused(const float* __restrict__ x, const float* __restrict__ c,
                          const float* __restrict__ bn_scale, const float* __restrict__ bn_bias,
                          const float* __restrict__ bn_mean, const float* __restrict__ bn_var,
                          const float* __restrict__ W0, const float* __restrict__ b0,
                          const float* __restrict__ W1, const float* __restrict__ b1,
                          const float* __restrict__ W2, const float* __restrict__ b2,
                          float* __restrict__ out, int N) {
    // LDS: h0 (64x48, stride 49) reused later as yt (64x32, stride 33)
    __shared__ float h0yt[ROWS * 49];
    __shared__ float h1p[ROWS * 129];
    __shared__ float h2p[ROWS * 129];
    __shared__ float ldp[4 * ROWS];

    const int tid  = threadIdx.x;
    const int lane = tid & 63;
    const int wu   = __builtin_amdgcn_readfirstlane(tid >> 6);  // wave id, SGPR
    const int r0   = blockIdx.x * ROWS;

    // ---- stage h0 with BN; copy xc passthrough to out cols 32..63 ----
    for (int idx = tid; idx < ROWS * CIN; idx += 256) {
        int r = idx / CIN, j = idx - r * CIN;
        int row = r0 + r;
        float v = (j < 32) ? x[(size_t)row * 64 + 32 + j] : c[(size_t)row * 16 + (j - 32)];
        float h = (v - bn_mean[j]) * rsqrtf(bn_var[j] + 1e-5f) * bn_scale[j] + bn_bias[j];
        h0yt[r * 49 + j] = h;
    }
    for (int idx = tid; idx < ROWS * 32; idx += 256) {
        int r = idx >> 5, j = idx & 31;
        out[(size_t)(r0 + r) * 64 + 32 + j] = x[(size_t)(r0 + r) * 64 + 32 + j];
    }

    // preload this lane's spline inputs t = xt[row][dim] for this wave's 8 dims
    float xtreg[8];
    #pragma unroll
    for (int p = 0; p < 8; ++p)
        xtreg[p] = x[(size_t)(r0 + lane) * 64 + wu * 8 + p];

    __syncthreads();

    // ---- GEMM0: h1 = swish(h0 @ W0 + b0). wave covers n in [wu*32, wu*32+32) ----
    {
        const int n0 = wu * 32;
        float acc[32];
        #pragma unroll
        for (int j = 0; j < 32; ++j) acc[j] = b0[n0 + j];
        float hv = h0yt[lane * 49];
        for (int k = 0; k < CIN; ++k) {
            float hvn = h0yt[lane * 49 + (k + 1 < CIN ? k + 1 : k)];
            const float* wr = W0 + k * NH1 + n0;   // wave-uniform -> s_load
            #pragma unroll
            for (int j = 0; j < 32; ++j) acc[j] = fmaf(hv, wr[j], acc[j]);
            hv = hvn;
        }
        #pragma unroll
        for (int j = 0; j < 32; ++j) h1p[lane * 129 + n0 + j] = swish_f(acc[j]);
    }
    __syncthreads();

    // ---- GEMM1: h2 = swish(h1 @ W1 + b1) ----
    {
        const int n0 = wu * 32;
        float acc[32];
        #pragma unroll
        for (int j = 0; j < 32; ++j) acc[j] = b1[n0 + j];
        float hv = h1p[lane * 129];
        for (int k = 0; k < NH1; ++k) {
            float hvn = h1p[lane * 129 + (k + 1 < NH1 ? k + 1 : k)];
            const float* wr = W1 + k * NH2 + n0;
            #pragma unroll
            for (int j = 0; j < 32; ++j) acc[j] = fmaf(hv, wr[j], acc[j]);
            hv = hvn;
        }
        #pragma unroll
        for (int j = 0; j < 32; ++j) h2p[lane * 129 + n0 + j] = swish_f(acc[j]);
    }
    __syncthreads();

    // ---- GEMM2 + spline. wave wu handles dims wu*8 .. wu*8+7; lane = row ----
    float ld_local = 0.f;
    for (int pass = 0; pass < 8; ++pass) {
        const int dim   = wu * 8 + pass;
        const int cbase = dim * SPLINE_DIM;
        float acc[SPLINE_DIM];
        #pragma unroll
        for (int j = 0; j < SPLINE_DIM; ++j) acc[j] = b2[cbase + j];
        float hv = h2p[lane * 129];
        for (int k = 0; k < NH2; ++k) {
            float hvn = h2p[lane * 129 + (k + 1 < NH2 ? k + 1 : k)];
            const float* wr = W2 + (size_t)k * NCOLS + cbase;  // wave-uniform -> s_load
            #pragma unroll
            for (int j = 0; j < SPLINE_DIM; ++j) acc[j] = fmaf(hv, wr[j], acc[j]);
            hv = hvn;
        }

        // ---- rational-quadratic spline on acc[0..46] ----
        float mW = acc[0], mH = acc[16];
        #pragma unroll
        for (int i = 1; i < 16; ++i) { mW = fmaxf(mW, acc[i]); mH = fmaxf(mH, acc[16 + i]); }
        float eW[16], eH[16];
        float sW = 0.f, sH = 0.f;
        #pragma unroll
        for (int i = 0; i < 16; ++i) { eW[i] = expf(acc[i] - mW);      sW += eW[i]; }
        #pragma unroll
        for (int i = 0; i < 16; ++i) { eH[i] = expf(acc[16 + i] - mH); sH += eH[i]; }
        float invW = 1.f / sW, invH = 1.f / sH;

        float t  = xtreg[pass];
        bool inb = (t >= 0.f) && (t <= 1.f);
        float tc = fminf(fmaxf(t, 0.f), 1.f);

        float cum = 0.f, cumy = 0.f;
        float xkb = 0.f, ykb = 0.f;
        float dxb = eW[0] * invW, dyb = eH[0] * invH;
        int idx = 0;
        #pragma unroll
        for (int i = 0; i < 16; ++i) {
            float dxi = eW[i] * invW, dyi = eH[i] * invH;
            bool cnd = (tc >= cum);     // xk_i <= tc
            idx = cnd ? i   : idx;
            xkb = cnd ? cum : xkb;
            ykb = cnd ? cumy: ykb;
            dxb = cnd ? dxi : dxb;
            dyb = cnd ? dyi : dyb;
            cum  += dxi;
            cumy += dyi;
        }
        // dk = [1, softplus(D0..D14), 1]; d0 = dk[idx], d1 = dk[idx+1]
        float a0 = 0.f, a1 = 0.f;
        #pragma unroll
        for (int j = 0; j < 15; ++j) {
            a0 = (j == idx - 1) ? acc[32 + j] : a0;
            a1 = (j == idx)     ? acc[32 + j] : a1;
        }
        float d0 = (idx == 0)  ? 1.f : softplus_f(a0);
        float d1 = (idx == 15) ? 1.f : softplus_f(a1);

        float xi  = (tc - xkb) / dxb;
        float s   = dyb / dxb;
        float xim = 1.f - xi;
        float x1m = xi * xim;
        float den = s + (d0 + d1 - 2.f * s) * x1m;
        float y_in = ykb + dyb * (s * xi * xi + d0 * x1m) / den;
        float dydx = s * s * (d1 * xi * xi + 2.f * s * x1m + d0 * xim * xim) / (den * den);

        float yv = inb ? y_in : t;
        ld_local += inb ? logf(dydx) : 0.f;
        h0yt[lane * 33 + dim] = yv;   // yt staging (h0 buffer is dead)
    }
    ldp[wu * ROWS + lane] = ld_local;
    __syncthreads();

    // ---- coalesced yt writeback + log_det reduction ----
    for (int idx = tid; idx < ROWS * 32; idx += 256) {
        int r = idx >> 5, j = idx & 31;
        out[(size_t)(r0 + r) * 64 + j] = h0yt[r * 33 + j];
    }
    if (tid < ROWS) {
        out[(size_t)N * 64 + r0 + tid] =
            ldp[tid] + ldp[ROWS + tid] + ldp[2 * ROWS + tid] + ldp[3 * ROWS + tid];
    }
}

extern "C" void kernel_launch(void* const* d_in, const int* in_sizes, int n_in,
                              void* d_out, int out_size, void* d_ws, size_t ws_size,
                              hipStream_t stream) {
    const float* x        = (const float*)d_in[0];
    const float* c        = (const float*)d_in[1];
    const float* bn_scale = (const float*)d_in[2];
    const float* bn_bias  = (const float*)d_in[3];
    const float* bn_mean  = (const float*)d_in[4];
    const float* bn_var   = (const float*)d_in[5];
    const float* W0       = (const float*)d_in[6];
    const float* b0       = (const float*)d_in[7];
    const float* W1       = (const float*)d_in[8];
    const float* b1       = (const float*)d_in[9];
    const float* W2       = (const float*)d_in[10];
    const float* b2       = (const float*)d_in[11];
    float* out = (float*)d_out;

    const int N = in_sizes[0] / 64;     // 65536
    const int blocks = N / ROWS;        // 1024
    nsc_fused<<<blocks, 256, 0, stream>>>(x, c, bn_scale, bn_bias, bn_mean, bn_var,
                                          W0, b0, W1, b1, W2, b2, out, N);
}

// Round 2
// 186.237 us; speedup vs baseline: 5.7177x; 5.7177x over previous
//
#include <hip/hip_runtime.h>
#include <math.h>

#define BN_EPS 1e-5f
#define ROWS 64

typedef __attribute__((ext_vector_type(8))) short short8;
typedef __attribute__((ext_vector_type(4))) float float4v;

__device__ __forceinline__ unsigned short f2bf(float f) {
    union { float f; unsigned int u; } v; v.f = f;
    unsigned int r = v.u + 0x7FFF + ((v.u >> 16) & 1);   // RNE
    return (unsigned short)(r >> 16);
}
__device__ __forceinline__ float softplus_f(float v) {
    float r = log1pf(__expf(-fabsf(v)));
    return v > 0.f ? v + r : r;
}
__device__ __forceinline__ float swish_f(float a) {
    return a / (1.f + __expf(-a));
}

// ---- weight prep: fp32 [k][n] -> bf16 [n][k] (transposed, padded) ----
// Wt0: [128][64]  (k 48..63 zero)   Wt1: [128][128]   Wt2: [1536][128] (col=dim*48+j, j=47 zero)
__global__ void prep_weights(const float* __restrict__ W0, const float* __restrict__ W1,
                             const float* __restrict__ W2,
                             unsigned short* __restrict__ Wt0, unsigned short* __restrict__ Wt1,
                             unsigned short* __restrict__ Wt2) {
    int e = blockIdx.x * 256 + threadIdx.x;
    if (e < 128 * 64) {
        int n = e >> 6, k = e & 63;
        Wt0[e] = f2bf(k < 48 ? W0[k * 128 + n] : 0.f);
        return;
    }
    e -= 128 * 64;
    if (e < 128 * 128) {
        int n = e >> 7, k = e & 127;
        Wt1[e] = f2bf(W1[k * 128 + n]);
        return;
    }
    e -= 128 * 128;
    if (e < 1536 * 128) {
        int col = e >> 7, k = e & 127;
        int d = col / 48, j = col - d * 48;
        Wt2[e] = f2bf(j < 47 ? W2[k * 1504 + d * 47 + j] : 0.f);
    }
}

__launch_bounds__(256, 2)
__global__ void nsc_mfma(const float* __restrict__ x, const float* __restrict__ c,
                         const float* __restrict__ bn_scale, const float* __restrict__ bn_bias,
                         const float* __restrict__ bn_mean, const float* __restrict__ bn_var,
                         const unsigned short* __restrict__ Wt0, const float* __restrict__ b0,
                         const unsigned short* __restrict__ Wt1, const float* __restrict__ b1,
                         const unsigned short* __restrict__ Wt2, const float* __restrict__ b2,
                         float* __restrict__ out, int N) {
    // region1 (0..17407):    h0 [64][72] bf16  ->  h2 [64][136] bf16  ->  yt [64][33] f32 + ldp
    // region2 (17408..):     h1 [64][136] bf16 ->  p  4x[64][52] f32
    __shared__ char smem[70656];
    unsigned short* h0 = (unsigned short*)smem;            // stride 72
    unsigned short* h2 = (unsigned short*)smem;            // stride 136
    float*          yt = (float*)smem;                     // stride 33
    float*          ldp = (float*)(smem + 8448);           // [4][64]
    unsigned short* h1 = (unsigned short*)(smem + 17408);  // stride 136

    const int tid  = threadIdx.x;
    const int lane = tid & 63;
    const int l    = lane & 15;          // tile row/col index
    const int q    = lane >> 4;          // quad
    const int wu   = __builtin_amdgcn_readfirstlane(tid >> 6);
    const int r0   = blockIdx.x * ROWS;
    float* pw = (float*)(smem + 17408) + wu * (64 * 52);   // per-wave p buffer, stride 52

    // ---- phase 1: BN -> h0 bf16 (K padded to 64); xc passthrough; xt preload ----
    for (int idx = tid; idx < 64 * 64; idx += 256) {
        int r = idx >> 6, j = idx & 63;
        float h = 0.f;
        if (j < 48) {
            int row = r0 + r;
            float v = (j < 32) ? x[(size_t)row * 64 + 32 + j] : c[(size_t)row * 16 + (j - 32)];
            h = (v - bn_mean[j]) * rsqrtf(bn_var[j] + BN_EPS) * bn_scale[j] + bn_bias[j];
        }
        h0[r * 72 + j] = f2bf(h);
    }
    for (int idx = tid; idx < 64 * 32; idx += 256) {
        int r = idx >> 5, j = idx & 31;
        out[(size_t)(r0 + r) * 64 + 32 + j] = x[(size_t)(r0 + r) * 64 + 32 + j];
    }
    float xtreg[8];
    {
        const float* xrow = x + (size_t)(r0 + lane) * 64 + wu * 8;
        *(float4v*)(xtreg)     = *(const float4v*)(xrow);
        *(float4v*)(xtreg + 4) = *(const float4v*)(xrow + 4);
    }
    __syncthreads();

    // ---- phase 2: GEMM0  h1 = swish(h0 @ W0 + b0), M=64 N=128 K=64(padded) ----
    {
        float4v acc[2][4];
        float4v z = {0.f, 0.f, 0.f, 0.f};
        #pragma unroll
        for (int nt = 0; nt < 2; ++nt)
            #pragma unroll
            for (int mt = 0; mt < 4; ++mt) acc[nt][mt] = z;
        #pragma unroll
        for (int ks = 0; ks < 2; ++ks) {
            short8 a[4];
            #pragma unroll
            for (int mt = 0; mt < 4; ++mt)
                a[mt] = *(const short8*)(h0 + (mt * 16 + l) * 72 + ks * 32 + (q << 3));
            #pragma unroll
            for (int nt = 0; nt < 2; ++nt) {
                int n0 = (wu * 2 + nt) * 16;
                short8 b = *(const short8*)(Wt0 + (n0 + l) * 64 + ks * 32 + (q << 3));
                #pragma unroll
                for (int mt = 0; mt < 4; ++mt)
                    acc[nt][mt] = __builtin_amdgcn_mfma_f32_16x16x32_bf16(a[mt], b, acc[nt][mt], 0, 0, 0);
            }
        }
        #pragma unroll
        for (int nt = 0; nt < 2; ++nt) {
            int n0 = (wu * 2 + nt) * 16;
            float bb = b0[n0 + l];
            #pragma unroll
            for (int mt = 0; mt < 4; ++mt)
                #pragma unroll
                for (int r = 0; r < 4; ++r)
                    h1[(mt * 16 + q * 4 + r) * 136 + n0 + l] = f2bf(swish_f(acc[nt][mt][r] + bb));
        }
    }
    __syncthreads();

    // ---- phase 3: GEMM1  h2 = swish(h1 @ W1 + b1), M=64 N=128 K=128 ----
    {
        float4v acc[2][4];
        float4v z = {0.f, 0.f, 0.f, 0.f};
        #pragma unroll
        for (int nt = 0; nt < 2; ++nt)
            #pragma unroll
            for (int mt = 0; mt < 4; ++mt) acc[nt][mt] = z;
        #pragma unroll
        for (int ks = 0; ks < 4; ++ks) {
            short8 a[4];
            #pragma unroll
            for (int mt = 0; mt < 4; ++mt)
                a[mt] = *(const short8*)(h1 + (mt * 16 + l) * 136 + ks * 32 + (q << 3));
            #pragma unroll
            for (int nt = 0; nt < 2; ++nt) {
                int n0 = (wu * 2 + nt) * 16;
                short8 b = *(const short8*)(Wt1 + (n0 + l) * 128 + ks * 32 + (q << 3));
                #pragma unroll
                for (int mt = 0; mt < 4; ++mt)
                    acc[nt][mt] = __builtin_amdgcn_mfma_f32_16x16x32_bf16(a[mt], b, acc[nt][mt], 0, 0, 0);
            }
        }
        #pragma unroll
        for (int nt = 0; nt < 2; ++nt) {
            int n0 = (wu * 2 + nt) * 16;
            float bb = b1[n0 + l];
            #pragma unroll
            for (int mt = 0; mt < 4; ++mt)
                #pragma unroll
                for (int r = 0; r < 4; ++r)
                    h2[(mt * 16 + q * 4 + r) * 136 + n0 + l] = f2bf(swish_f(acc[nt][mt][r] + bb));
        }
    }
    __syncthreads();

    // ---- phase 4: hold all A-fragments of h2 in registers ----
    short8 af[4][4];
    #pragma unroll
    for (int mt = 0; mt < 4; ++mt)
        #pragma unroll
        for (int ks = 0; ks < 4; ++ks)
            af[mt][ks] = *(const short8*)(h2 + (mt * 16 + l) * 136 + ks * 32 + (q << 3));
    __syncthreads();   // h2 dead after this; yt may alias it

    // ---- GEMM2 + spline: wave handles dims wu*8 .. wu*8+7 over all 64 rows ----
    float ld_local = 0.f;
    for (int pass = 0; pass < 8; ++pass) {
        const int d  = wu * 8 + pass;
        const int cb = d * 48;
        float4v acc[3][4];
        float4v z = {0.f, 0.f, 0.f, 0.f};
        #pragma unroll
        for (int nt = 0; nt < 3; ++nt)
            #pragma unroll
            for (int mt = 0; mt < 4; ++mt) acc[nt][mt] = z;
        #pragma unroll
        for (int ks = 0; ks < 4; ++ks) {
            #pragma unroll
            for (int nt = 0; nt < 3; ++nt) {
                short8 b = *(const short8*)(Wt2 + (size_t)(cb + nt * 16 + l) * 128 + ks * 32 + (q << 3));
                #pragma unroll
                for (int mt = 0; mt < 4; ++mt)
                    acc[nt][mt] = __builtin_amdgcn_mfma_f32_16x16x32_bf16(af[mt][ks], b, acc[nt][mt], 0, 0, 0);
            }
        }
        // bias + transpose through per-wave LDS buffer (stride 52 words)
        #pragma unroll
        for (int nt = 0; nt < 3; ++nt) {
            int j = nt * 16 + l;
            float bj = (j < 47) ? b2[d * 47 + j] : 0.f;
            #pragma unroll
            for (int mt = 0; mt < 4; ++mt)
                #pragma unroll
                for (int r = 0; r < 4; ++r)
                    pw[(mt * 16 + q * 4 + r) * 52 + j] = acc[nt][mt][r] + bj;
        }
        asm volatile("s_waitcnt lgkmcnt(0)" ::: "memory");   // wave-local RAW on pw
        float pr[48];
        #pragma unroll
        for (int j = 0; j < 12; ++j)
            *(float4v*)(pr + j * 4) = *(const float4v*)(pw + lane * 52 + j * 4);

        // ---- rational-quadratic spline (round-1 verified math) ----
        float mWv = pr[0], mHv = pr[16];
        #pragma unroll
        for (int i = 1; i < 16; ++i) { mWv = fmaxf(mWv, pr[i]); mHv = fmaxf(mHv, pr[16 + i]); }
        float sW = 0.f, sH = 0.f;
        #pragma unroll
        for (int i = 0; i < 16; ++i) { pr[i] = __expf(pr[i] - mWv); sW += pr[i]; }
        #pragma unroll
        for (int i = 0; i < 16; ++i) { pr[16 + i] = __expf(pr[16 + i] - mHv); sH += pr[16 + i]; }
        float invW = 1.f / sW, invH = 1.f / sH;

        float t  = xtreg[pass];
        bool inb = (t >= 0.f) && (t <= 1.f);
        float tc = fminf(fmaxf(t, 0.f), 1.f);

        float cum = 0.f, cumy = 0.f, xkb = 0.f, ykb = 0.f;
        float dxb = pr[0] * invW, dyb = pr[16] * invH;
        int idx = 0;
        #pragma unroll
        for (int i = 0; i < 16; ++i) {
            float dxi = pr[i] * invW, dyi = pr[16 + i] * invH;
            bool cnd = (tc >= cum);
            idx = cnd ? i : idx;
            xkb = cnd ? cum : xkb;
            ykb = cnd ? cumy : ykb;
            dxb = cnd ? dxi : dxb;
            dyb = cnd ? dyi : dyb;
            cum  += dxi;
            cumy += dyi;
        }
        float a0 = 0.f, a1 = 0.f;
        #pragma unroll
        for (int j = 0; j < 15; ++j) {
            a0 = (j == idx - 1) ? pr[32 + j] : a0;
            a1 = (j == idx)     ? pr[32 + j] : a1;
        }
        float d0 = (idx == 0)  ? 1.f : softplus_f(a0);
        float d1 = (idx == 15) ? 1.f : softplus_f(a1);

        float xi  = (tc - xkb) / dxb;
        float s   = dyb / dxb;
        float xim = 1.f - xi;
        float x1m = xi * xim;
        float den = s + (d0 + d1 - 2.f * s) * x1m;
        float y_in = ykb + dyb * (s * xi * xi + d0 * x1m) / den;
        float dydx = s * s * (d1 * xi * xi + 2.f * s * x1m + d0 * xim * xim) / (den * den);

        yt[lane * 33 + d] = inb ? y_in : t;
        ld_local += inb ? __logf(dydx) : 0.f;
    }
    ldp[wu * 64 + lane] = ld_local;
    __syncthreads();

    // ---- coalesced writeback ----
    for (int idx = tid; idx < 64 * 32; idx += 256) {
        int r = idx >> 5, j = idx & 31;
        out[(size_t)(r0 + r) * 64 + j] = yt[r * 33 + j];
    }
    if (tid < 64) {
        out[(size_t)N * 64 + r0 + tid] =
            ldp[tid] + ldp[64 + tid] + ldp[128 + tid] + ldp[192 + tid];
    }
}

extern "C" void kernel_launch(void* const* d_in, const int* in_sizes, int n_in,
                              void* d_out, int out_size, void* d_ws, size_t ws_size,
                              hipStream_t stream) {
    const float* x        = (const float*)d_in[0];
    const float* c        = (const float*)d_in[1];
    const float* bn_scale = (const float*)d_in[2];
    const float* bn_bias  = (const float*)d_in[3];
    const float* bn_mean  = (const float*)d_in[4];
    const float* bn_var   = (const float*)d_in[5];
    const float* W0       = (const float*)d_in[6];
    const float* b0       = (const float*)d_in[7];
    const float* W1       = (const float*)d_in[8];
    const float* b1       = (const float*)d_in[9];
    const float* W2       = (const float*)d_in[10];
    const float* b2       = (const float*)d_in[11];
    float* out = (float*)d_out;

    unsigned short* Wt0 = (unsigned short*)d_ws;           // 128*64
    unsigned short* Wt1 = Wt0 + 128 * 64;                  // 128*128
    unsigned short* Wt2 = Wt1 + 128 * 128;                 // 1536*128

    const int N = in_sizes[0] / 64;
    prep_weights<<<(128 * 64 + 128 * 128 + 1536 * 128 + 255) / 256, 256, 0, stream>>>(
        W0, W1, W2, Wt0, Wt1, Wt2);
    nsc_mfma<<<N / ROWS, 256, 0, stream>>>(x, c, bn_scale, bn_bias, bn_mean, bn_var,
                                           Wt0, b0, Wt1, b1, Wt2, b2, out, N);
}

// Round 3
// 172.030 us; speedup vs baseline: 6.1899x; 1.0826x over previous
//
#include <hip/hip_runtime.h>
#include <math.h>

#define BN_EPS 1e-5f
#define ROWS 64

typedef __attribute__((ext_vector_type(8))) short short8;
typedef __attribute__((ext_vector_type(4))) float float4v;

__device__ __forceinline__ unsigned short f2bf(float f) {
    union { float f; unsigned int u; } v; v.f = f;
    unsigned int r = v.u + 0x7FFF + ((v.u >> 16) & 1);   // RNE
    return (unsigned short)(r >> 16);
}
__device__ __forceinline__ float softplus_f(float v) {
    float r = log1pf(__expf(-fabsf(v)));
    return v > 0.f ? v + r : r;
}
__device__ __forceinline__ float swish_f(float a) {
    return a / (1.f + __expf(-a));
}

// ---- weight prep: fp32 [k][n] -> bf16 [n][k] (transposed, padded); b2 padded to [32][48] ----
__global__ void prep_weights(const float* __restrict__ W0, const float* __restrict__ W1,
                             const float* __restrict__ W2, const float* __restrict__ b2,
                             unsigned short* __restrict__ Wt0, unsigned short* __restrict__ Wt1,
                             unsigned short* __restrict__ Wt2, float* __restrict__ b2p) {
    int e = blockIdx.x * 256 + threadIdx.x;
    if (e < 128 * 64) {
        int n = e >> 6, k = e & 63;
        Wt0[e] = f2bf(k < 48 ? W0[k * 128 + n] : 0.f);
        return;
    }
    e -= 128 * 64;
    if (e < 128 * 128) {
        int n = e >> 7, k = e & 127;
        Wt1[e] = f2bf(W1[k * 128 + n]);
        return;
    }
    e -= 128 * 128;
    if (e < 1536 * 128) {
        int col = e >> 7, k = e & 127;
        int d = col / 48, j = col - d * 48;
        Wt2[e] = f2bf(j < 47 ? W2[k * 1504 + d * 47 + j] : 0.f);
        return;
    }
    e -= 1536 * 128;
    if (e < 32 * 48) {
        int d = e / 48, j = e - d * 48;
        b2p[e] = (j < 47) ? b2[d * 47 + j] : 0.f;
    }
}

__launch_bounds__(256, 4)
__global__ void nsc_mfma(const float* __restrict__ x, const float* __restrict__ c,
                         const float* __restrict__ bn_scale, const float* __restrict__ bn_bias,
                         const float* __restrict__ bn_mean, const float* __restrict__ bn_var,
                         const unsigned short* __restrict__ Wt0, const float* __restrict__ b0,
                         const unsigned short* __restrict__ Wt1, const float* __restrict__ b1,
                         const unsigned short* __restrict__ Wt2, const float* __restrict__ b2p,
                         float* __restrict__ out, int N) {
    // region A [0,17408):       h0 [64][72] bf16  ->  h2 [64][136] bf16 (live through GEMM2)
    // region B [17408,38912):   h1 [64][136] bf16 ->  pw 4x[64][20] f32 (20480) + ldp [4][64] f32
    __shared__ __align__(16) char smem[38912];
    unsigned short* h0 = (unsigned short*)smem;            // stride 72
    unsigned short* h2 = (unsigned short*)smem;            // stride 136
    unsigned short* h1 = (unsigned short*)(smem + 17408);  // stride 136
    float*          ldp = (float*)(smem + 17408 + 20480);  // [4][64]

    const int tid  = threadIdx.x;
    const int lane = tid & 63;
    const int l    = lane & 15;          // tile index
    const int q    = lane >> 4;          // quad
    const int wu   = __builtin_amdgcn_readfirstlane(tid >> 6);
    const int r0   = blockIdx.x * ROWS;
    float* pw = (float*)(smem + 17408) + wu * (64 * 20);   // per-wave staging, stride 20

    // ---- phase 1: BN -> h0 bf16 (K padded to 64); xc passthrough ----
    for (int idx = tid; idx < 64 * 64; idx += 256) {
        int r = idx >> 6, j = idx & 63;
        float h = 0.f;
        if (j < 48) {
            int row = r0 + r;
            float v = (j < 32) ? x[(size_t)row * 64 + 32 + j] : c[(size_t)row * 16 + (j - 32)];
            h = (v - bn_mean[j]) * rsqrtf(bn_var[j] + BN_EPS) * bn_scale[j] + bn_bias[j];
        }
        h0[r * 72 + j] = f2bf(h);
    }
    for (int idx = tid; idx < 64 * 32; idx += 256) {
        int r = idx >> 5, j = idx & 31;
        out[(size_t)(r0 + r) * 64 + 32 + j] = x[(size_t)(r0 + r) * 64 + 32 + j];
    }
    __syncthreads();

    // ---- phase 2: GEMM0  h1 = swish(h0 @ W0 + b0), M=64 N=128 K=64(padded) ----
    {
        float4v acc[2][4];
        float4v z = {0.f, 0.f, 0.f, 0.f};
        #pragma unroll
        for (int nt = 0; nt < 2; ++nt)
            #pragma unroll
            for (int mt = 0; mt < 4; ++mt) acc[nt][mt] = z;
        #pragma unroll
        for (int ks = 0; ks < 2; ++ks) {
            short8 a[4];
            #pragma unroll
            for (int mt = 0; mt < 4; ++mt)
                a[mt] = *(const short8*)(h0 + (mt * 16 + l) * 72 + ks * 32 + (q << 3));
            #pragma unroll
            for (int nt = 0; nt < 2; ++nt) {
                int n0 = (wu * 2 + nt) * 16;
                short8 b = *(const short8*)(Wt0 + (n0 + l) * 64 + ks * 32 + (q << 3));
                #pragma unroll
                for (int mt = 0; mt < 4; ++mt)
                    acc[nt][mt] = __builtin_amdgcn_mfma_f32_16x16x32_bf16(a[mt], b, acc[nt][mt], 0, 0, 0);
            }
        }
        #pragma unroll
        for (int nt = 0; nt < 2; ++nt) {
            int n0 = (wu * 2 + nt) * 16;
            float bb = b0[n0 + l];
            #pragma unroll
            for (int mt = 0; mt < 4; ++mt)
                #pragma unroll
                for (int r = 0; r < 4; ++r)
                    h1[(mt * 16 + q * 4 + r) * 136 + n0 + l] = f2bf(swish_f(acc[nt][mt][r] + bb));
        }
    }
    __syncthreads();

    // ---- phase 3: GEMM1  h2 = swish(h1 @ W1 + b1), M=64 N=128 K=128 ----
    {
        float4v acc[2][4];
        float4v z = {0.f, 0.f, 0.f, 0.f};
        #pragma unroll
        for (int nt = 0; nt < 2; ++nt)
            #pragma unroll
            for (int mt = 0; mt < 4; ++mt) acc[nt][mt] = z;
        #pragma unroll
        for (int ks = 0; ks < 4; ++ks) {
            short8 a[4];
            #pragma unroll
            for (int mt = 0; mt < 4; ++mt)
                a[mt] = *(const short8*)(h1 + (mt * 16 + l) * 136 + ks * 32 + (q << 3));
            #pragma unroll
            for (int nt = 0; nt < 2; ++nt) {
                int n0 = (wu * 2 + nt) * 16;
                short8 b = *(const short8*)(Wt1 + (n0 + l) * 128 + ks * 32 + (q << 3));
                #pragma unroll
                for (int mt = 0; mt < 4; ++mt)
                    acc[nt][mt] = __builtin_amdgcn_mfma_f32_16x16x32_bf16(a[mt], b, acc[nt][mt], 0, 0, 0);
            }
        }
        #pragma unroll
        for (int nt = 0; nt < 2; ++nt) {
            int n0 = (wu * 2 + nt) * 16;
            float bb = b1[n0 + l];
            #pragma unroll
            for (int mt = 0; mt < 4; ++mt)
                #pragma unroll
                for (int r = 0; r < 4; ++r)
                    h2[(mt * 16 + q * 4 + r) * 136 + n0 + l] = f2bf(swish_f(acc[nt][mt][r] + bb));
        }
    }
    __syncthreads();   // h1 dead -> pw may reuse region B; h2 live in region A

    // ---- phase 4: GEMM2 (swapped: p^T tiles) + 3-stage spline. wave: dims wu*8..wu*8+7 ----
    float ld_local = 0.f;
    float yreg[8];
    for (int pass = 0; pass < 8; ++pass) {
        const int d = wu * 8 + pass;
        float4v acc[3][4];
        float4v z = {0.f, 0.f, 0.f, 0.f};
        #pragma unroll
        for (int jt = 0; jt < 3; ++jt)
            #pragma unroll
            for (int smt = 0; smt < 4; ++smt) acc[jt][smt] = z;
        #pragma unroll
        for (int ks = 0; ks < 4; ++ks) {
            short8 bf[4];
            #pragma unroll
            for (int smt = 0; smt < 4; ++smt)
                bf[smt] = *(const short8*)(h2 + (smt * 16 + l) * 136 + ks * 32 + (q << 3));
            #pragma unroll
            for (int jt = 0; jt < 3; ++jt) {
                short8 a = *(const short8*)(Wt2 + (size_t)(d * 48 + jt * 16 + l) * 128 + ks * 32 + (q << 3));
                #pragma unroll
                for (int smt = 0; smt < 4; ++smt)
                    acc[jt][smt] = __builtin_amdgcn_mfma_f32_16x16x32_bf16(a, bf[smt], acc[jt][smt], 0, 0, 0);
            }
        }

        float t  = x[(size_t)(r0 + lane) * 64 + d];
        bool inb = (t >= 0.f) && (t <= 1.f);
        float tc = fminf(fmaxf(t, 0.f), 1.f);
        float pr[16];

        // ---- stage W (jt=0): softmax + bin search ----
        {
            float4v bj = *(const float4v*)(b2p + d * 48 + (q << 2));
            #pragma unroll
            for (int smt = 0; smt < 4; ++smt)
                *(float4v*)(pw + (smt * 16 + l) * 20 + (q << 2)) = acc[0][smt] + bj;
            asm volatile("s_waitcnt lgkmcnt(0)" ::: "memory");
            #pragma unroll
            for (int c2 = 0; c2 < 4; ++c2)
                *(float4v*)(pr + c2 * 4) = *(const float4v*)(pw + lane * 20 + c2 * 4);
        }
        float mW = pr[0];
        #pragma unroll
        for (int i = 1; i < 16; ++i) mW = fmaxf(mW, pr[i]);
        float sW = 0.f;
        #pragma unroll
        for (int i = 0; i < 16; ++i) { pr[i] = __expf(pr[i] - mW); sW += pr[i]; }
        float invW = 1.f / sW;
        float cum = 0.f, xkb = 0.f, dxb = pr[0] * invW;
        int idx = 0;
        #pragma unroll
        for (int i = 0; i < 16; ++i) {
            float dxi = pr[i] * invW;
            bool cnd = (tc >= cum);
            idx = cnd ? i   : idx;
            xkb = cnd ? cum : xkb;
            dxb = cnd ? dxi : dxb;
            cum += dxi;
        }

        // ---- stage H (jt=1): softmax + ykb/dyb ----
        {
            float4v bj = *(const float4v*)(b2p + d * 48 + 16 + (q << 2));
            #pragma unroll
            for (int smt = 0; smt < 4; ++smt)
                *(float4v*)(pw + (smt * 16 + l) * 20 + (q << 2)) = acc[1][smt] + bj;
            asm volatile("s_waitcnt lgkmcnt(0)" ::: "memory");
            #pragma unroll
            for (int c2 = 0; c2 < 4; ++c2)
                *(float4v*)(pr + c2 * 4) = *(const float4v*)(pw + lane * 20 + c2 * 4);
        }
        float mH = pr[0];
        #pragma unroll
        for (int i = 1; i < 16; ++i) mH = fmaxf(mH, pr[i]);
        float sH = 0.f;
        #pragma unroll
        for (int i = 0; i < 16; ++i) { pr[i] = __expf(pr[i] - mH); sH += pr[i]; }
        float invH = 1.f / sH;
        float ykb = 0.f, dyb = pr[0] * invH;
        #pragma unroll
        for (int i = 0; i < 16; ++i) {
            float dyi = pr[i] * invH;
            ykb += (i < idx) ? dyi : 0.f;
            dyb  = (i == idx) ? dyi : dyb;
        }

        // ---- stage D (jt=2): slopes ----
        {
            float4v bj = *(const float4v*)(b2p + d * 48 + 32 + (q << 2));
            #pragma unroll
            for (int smt = 0; smt < 4; ++smt)
                *(float4v*)(pw + (smt * 16 + l) * 20 + (q << 2)) = acc[2][smt] + bj;
            asm volatile("s_waitcnt lgkmcnt(0)" ::: "memory");
            #pragma unroll
            for (int c2 = 0; c2 < 4; ++c2)
                *(float4v*)(pr + c2 * 4) = *(const float4v*)(pw + lane * 20 + c2 * 4);
        }
        float a0 = 0.f, a1 = 0.f;
        #pragma unroll
        for (int i = 0; i < 15; ++i) {
            a0 = (i == idx - 1) ? pr[i] : a0;
            a1 = (i == idx)     ? pr[i] : a1;
        }
        float d0 = (idx == 0)  ? 1.f : softplus_f(a0);
        float d1 = (idx == 15) ? 1.f : softplus_f(a1);

        float xi  = (tc - xkb) / dxb;
        float s   = dyb / dxb;
        float xim = 1.f - xi;
        float x1m = xi * xim;
        float den = s + (d0 + d1 - 2.f * s) * x1m;
        float y_in = ykb + dyb * (s * xi * xi + d0 * x1m) / den;
        float dydx = s * s * (d1 * xi * xi + 2.f * s * x1m + d0 * xim * xim) / (den * den);

        yreg[pass] = inb ? y_in : t;
        ld_local += inb ? __logf(dydx) : 0.f;
    }

    // ---- epilogue: y from registers (lane owns sample r0+lane, dims wu*8..+7) ----
    {
        float4v* o = (float4v*)(out + (size_t)(r0 + lane) * 64 + wu * 8);
        o[0] = *(const float4v*)(yreg);
        o[1] = *(const float4v*)(yreg + 4);
    }
    ldp[wu * 64 + lane] = ld_local;
    __syncthreads();
    if (tid < 64) {
        out[(size_t)N * 64 + r0 + tid] =
            ldp[tid] + ldp[64 + tid] + ldp[128 + tid] + ldp[192 + tid];
    }
}

extern "C" void kernel_launch(void* const* d_in, const int* in_sizes, int n_in,
                              void* d_out, int out_size, void* d_ws, size_t ws_size,
                              hipStream_t stream) {
    const float* x        = (const float*)d_in[0];
    const float* c        = (const float*)d_in[1];
    const float* bn_scale = (const float*)d_in[2];
    const float* bn_bias  = (const float*)d_in[3];
    const float* bn_mean  = (const float*)d_in[4];
    const float* bn_var   = (const float*)d_in[5];
    const float* W0       = (const float*)d_in[6];
    const float* b0       = (const float*)d_in[7];
    const float* W1       = (const float*)d_in[8];
    const float* b1       = (const float*)d_in[9];
    const float* W2       = (const float*)d_in[10];
    const float* b2       = (const float*)d_in[11];
    float* out = (float*)d_out;

    unsigned short* Wt0 = (unsigned short*)d_ws;           // 128*64
    unsigned short* Wt1 = Wt0 + 128 * 64;                  // 128*128
    unsigned short* Wt2 = Wt1 + 128 * 128;                 // 1536*128
    float*          b2p = (float*)(Wt2 + 1536 * 128);      // 32*48

    const int N = in_sizes[0] / 64;
    const int prep_elems = 128 * 64 + 128 * 128 + 1536 * 128 + 32 * 48;
    prep_weights<<<(prep_elems + 255) / 256, 256, 0, stream>>>(
        W0, W1, W2, b2, Wt0, Wt1, Wt2, b2p);
    nsc_mfma<<<N / ROWS, 256, 0, stream>>>(x, c, bn_scale, bn_bias, bn_mean, bn_var,
                                           Wt0, b0, Wt1, b1, Wt2, b2p, out, N);
}